// Round 15
// baseline (107.637 us; speedup 1.0000x reference)
//
#include <hip/hip_runtime.h>
#include <cstdint>
#include <cstddef>

#define B_ 4
#define L_ 4096
#define E_ 1024
#define H_ 16
#define D_ 64
#define BH_ 64
#define ST2_ 4160        // 4096 kv + 64 ksum (fp32 partials)
#define NCH_ 16
#define RPC_ (L_/NCH_)   // 256 k-rows per chunk
#define NT_ (RPC_/32)    // 8 tiles of 32 k-rows
#define LDK_ 68          // padded LDS row stride (floats): 2-way (free) gathers

typedef __attribute__((ext_vector_type(8))) short short8v;
typedef __attribute__((ext_vector_type(4))) float f32x4;

__device__ __forceinline__ float sigk(float x) {
    // sigmoid(0.6053*x - 4.102) = 1/(1+exp(4.102 - 0.6053*x))
    return __builtin_amdgcn_rcpf(1.0f + __expf(4.102f - 0.6053f * x));
}
// fp32 -> bf16 (RNE) and back, bit ops only
__device__ __forceinline__ unsigned short bfh(float f) {
    union { float f; unsigned u; } v; v.f = f;
    const unsigned r = v.u + 0x7fffu + ((v.u >> 16) & 1u);
    return (unsigned short)(r >> 16);
}
__device__ __forceinline__ float bf2f(unsigned short s) {
    union { unsigned u; float f; } v; v.u = ((unsigned)s) << 16;
    return v.f;
}

// MFMA 16x16x32_bf16 layouts (HW-verified, learn_hip m89/m156/m162):
//   A: lane l holds A[m=l&15][k=4*(l>>4)+(j&3)+16*(j>>2)], j=0..7
//   B: lane l holds B[k(same)][n=l&15]
//   C: lane l, reg r holds C[row=4*(l>>4)+r][col=l&15]

// ---------------- Kernel 1: partial kv[d][e] per (b,h,chunk) ----------------
// VECTORIZED staging (the R8-R14 sin was per-lane dword gathers: 256B/instr
// in 4x64B segments -- 4x the VMEM instructions of K3's float4 path, which
// streams the same bytes in ~1/6 the time). Raw K,V tiles staged row-major
// (stride 68) via coalesced float4 (1KB/instr); fragments gathered from LDS
// (2-way conflicts = free). Depth-2 reg prefetch + raw s_barrier with
// lgkmcnt-only (counted vmcnt preserved across barrier) as validated in R13.
__global__ void __launch_bounds__(256) kv_partial_kernel(
    const float* __restrict__ K, const float* __restrict__ V,
    float* __restrict__ partial)
{
    __shared__ float raw[2][2][32 * LDK_];   // [buf][0=K,1=V], 34 KB

    const int ch = blockIdx.x & (NCH_ - 1);
    const int bh = blockIdx.x / NCH_;
    const int b = bh >> 4, h = bh & 15;
    const int tid = threadIdx.x;
    const int w = tid >> 6, l = tid & 63;
    const int g = l >> 4, m = l & 15;
    const int k4 = g << 2;
    const int colA = (w << 4) + m;      // A d-column for this wave
    const int r0 = tid >> 4;            // staging row (+16 per round)
    const int c4 = (tid & 15) << 2;     // staging col (float4)

    const float* Kg = K + (size_t)(b * L_ + ch * RPC_) * E_ + h * D_;
    const float* Vg = V + (size_t)(b * L_ + ch * RPC_) * E_ + h * D_;

    f32x4 acc[4];
    #pragma unroll
    for (int t = 0; t < 4; ++t) acc[t] = (f32x4){0.f, 0.f, 0.f, 0.f};
    float ksacc = 0.f;

    float4 kreg[2][2], vreg[2][2];   // [slot][round]
    // prologue: load tiles 0,1 into slots 0,1 (coalesced float4)
    #pragma unroll
    for (int s = 0; s < 2; ++s)
        #pragma unroll
        for (int rr = 0; rr < 2; ++rr) {
            const size_t go = (size_t)((s << 5) + r0 + (rr << 4)) * E_ + c4;
            kreg[s][rr] = *(const float4*)(Kg + go);
            vreg[s][rr] = *(const float4*)(Vg + go);
        }
    // stage tile 0 into buf 0 (counted vmcnt: waits slot-0 loads only)
    #pragma unroll
    for (int rr = 0; rr < 2; ++rr) {
        const int ro = (r0 + (rr << 4)) * LDK_ + c4;
        *(float4*)&raw[0][0][ro] = kreg[0][rr];
        *(float4*)&raw[0][1][ro] = vreg[0][rr];
    }
    asm volatile("s_waitcnt lgkmcnt(0)" ::: "memory");
    __builtin_amdgcn_sched_barrier(0);
    __builtin_amdgcn_s_barrier();

    #pragma unroll 2
    for (int t = 0; t < NT_; ++t) {
        const int cur = t & 1, nxt = cur ^ 1;
        // 1. stage tile t+1 (regs slot nxt) into raw[nxt]
        if (t + 1 < NT_) {
            #pragma unroll
            for (int rr = 0; rr < 2; ++rr) {
                const int ro = (r0 + (rr << 4)) * LDK_ + c4;
                *(float4*)&raw[nxt][0][ro] = kreg[nxt][rr];
                *(float4*)&raw[nxt][1][ro] = vreg[nxt][rr];
            }
        }
        // 2. issue tile t+2 loads into slot cur (just freed)
        if (t + 2 < NT_) {
            #pragma unroll
            for (int rr = 0; rr < 2; ++rr) {
                const size_t go =
                    (size_t)(((t + 2) << 5) + r0 + (rr << 4)) * E_ + c4;
                kreg[cur][rr] = *(const float4*)(Kg + go);
                vreg[cur][rr] = *(const float4*)(Vg + go);
            }
        }
        __builtin_amdgcn_sched_barrier(0);   // keep load issue up here
        // 3. compute from raw[cur]: A = phi(K) gather; B = V hi/lo gather.
        //    Gathers are 2-way bank-aliased (stride 68) = free.
        {
            short8v Ah;
            #pragma unroll
            for (int j = 0; j < 8; ++j) {
                const int k = k4 + (j & 3) + ((j >> 2) << 4);
                const float kvv = raw[cur][0][k * LDK_ + colA];
                const unsigned short hb = bfh(sigk(kvv));
                Ah[j] = (short)hb;
                ksacc += bf2f(hb);        // SAME rounded weights as the MFMA
            }
            #pragma unroll
            for (int tt = 0; tt < 4; ++tt) {
                short8v Bh, Bl;
                #pragma unroll
                for (int j = 0; j < 8; ++j) {
                    const int k = k4 + (j & 3) + ((j >> 2) << 4);
                    const float vv = raw[cur][1][k * LDK_ + (tt << 4) + m];
                    const unsigned short hv = bfh(vv);
                    Bh[j] = (short)hv;
                    Bl[j] = (short)bfh(vv - bf2f(hv));
                }
                acc[tt] = __builtin_amdgcn_mfma_f32_16x16x32_bf16(Ah, Bh, acc[tt], 0, 0, 0);
                acc[tt] = __builtin_amdgcn_mfma_f32_16x16x32_bf16(Ah, Bl, acc[tt], 0, 0, 0);
            }
        }
        // 4. own ds ops done, then raw barrier -- NO vmcnt drain
        asm volatile("s_waitcnt lgkmcnt(0)" ::: "memory");
        __builtin_amdgcn_sched_barrier(0);
        __builtin_amdgcn_s_barrier();
    }

    // ksum[d]: combine the 4 lane-groups (same m, different k coverage)
    ksacc += __shfl_xor(ksacc, 16);
    ksacc += __shfl_xor(ksacc, 32);

    const size_t pbase = ((size_t)ch * BH_ + bh) * ST2_;
    #pragma unroll
    for (int tt = 0; tt < 4; ++tt)
        #pragma unroll
        for (int r = 0; r < 4; ++r)
            partial[pbase + (size_t)((w << 4) + k4 + r) * 64 + (tt << 4) + m]
                = acc[tt][r];
    if (g == 0) partial[pbase + 4096 + (w << 4) + m] = ksacc;
}

// ---- Kernel 2: reduce partials -> fragment-ordered kv2H / kv2L + ksum ----
// Each thread reduces an even/odd d-pair at one e: the pair lands in the SAME
// fragment u32 (jj even/odd <-> d even/odd), so hi and lo regions are packed
// u32 arrays that K3 copies straight.  Layout: u32[sp(8)][lane(64)][jq(4)].
__global__ void __launch_bounds__(256) kv_reduce_kernel(
    const float* __restrict__ partial, unsigned* __restrict__ kv2H,
    unsigned* __restrict__ kv2L, float* __restrict__ ksumf)
{
    const int bh = blockIdx.x >> 2, part = blockIdx.x & 3;
    const int tid = threadIdx.x;
    const int e = tid & 63;
    #pragma unroll
    for (int it = 0; it < 2; ++it) {
        const int pr = (tid >> 6) + (it << 2);       // 0..7 pair index
        const int d0 = (part << 4) + (pr << 1);      // even d
        float s0 = 0.f, s1 = 0.f;
        #pragma unroll
        for (int c = 0; c < NCH_; ++c) {
            const size_t pb = ((size_t)c * BH_ + bh) * ST2_;
            s0 += partial[pb + (d0 << 6) + e];
            s1 += partial[pb + ((d0 + 1) << 6) + e];
        }
        const unsigned short h0 = bfh(s0), h1 = bfh(s1);
        const unsigned short l0 = bfh(s0 - bf2f(h0));
        const unsigned short l1 = bfh(s1 - bf2f(h1));
        const int kk = d0 & 31;
        const int gg = (kk & 15) >> 2;
        const int jq = ((kk & 3) >> 1) + ((kk >> 4) << 1);   // jj>>1
        const int lane = (e & 15) + (gg << 4);
        const int sp = ((d0 >> 5) << 2) + (e >> 4);
        const size_t idx = (size_t)bh * 2048 + (((sp << 6) + lane) << 2) + jq;
        kv2H[idx] = (unsigned)h0 | ((unsigned)h1 << 16);
        kv2L[idx] = (unsigned)l0 | ((unsigned)l1 << 16);
    }
    if (part == 0 && tid < 64) {
        float s = 0.f;
        #pragma unroll
        for (int c = 0; c < NCH_; ++c)
            s += partial[((size_t)c * BH_ + bh) * ST2_ + 4096 + tid];
        ksumf[bh * 64 + tid] = s;
    }
}

// ---------------- Kernel 3: out = (phiQ @ kv) / (phiQ @ ksum) ----------------
// kvH/kvL staged by straight uint4 copy into short8v[slot][lane] (16B lane
// stride -> conflict-free b128 reads).  Qt: coalesced global float4 reads,
// 2-way-free LDS writes, 4-way (1.58x) scalar fragment gathers.
__global__ void __launch_bounds__(256) attn_out_kernel(
    const float* __restrict__ Q, const unsigned* __restrict__ kv2H,
    const unsigned* __restrict__ kv2L, const float* __restrict__ ksumf,
    float* __restrict__ out)
{
    __shared__ short8v kvH[8 * 64];   // 8 KB
    __shared__ short8v kvL[8 * 64];   // 8 KB
    __shared__ float Qt[64 * 65];     // 16.25 KB

    const int bh = blockIdx.x >> 6, qb = blockIdx.x & 63;
    const int b = bh >> 4, h = bh & 15;
    const int tid = threadIdx.x;
    const int w = tid >> 6, l = tid & 63;
    const int g = l >> 4, m = l & 15;
    const int k4 = g << 2;
    const int rowb0 = qb << 6;

    {   // stage kv fragments: straight copy, coalesced & conflict-free
        const uint4* srcH = (const uint4*)(kv2H + (size_t)bh * 2048);
        const uint4* srcL = (const uint4*)(kv2L + (size_t)bh * 2048);
        uint4* dH = (uint4*)kvH;
        uint4* dL = (uint4*)kvL;
        dH[tid]       = srcH[tid];
        dH[tid + 256] = srcH[tid + 256];
        dL[tid]       = srcL[tid];
        dL[tid + 256] = srcL[tid + 256];
    }
    // stage 64 Q rows (coalesced float4 reads; 2-way-free scalar LDS writes)
    #pragma unroll
    for (int i = 0; i < 4; ++i) {
        const int idx = tid + (i << 8);
        const int r = idx >> 4, c4i = (idx & 15) << 2;
        const float4 qv = *(const float4*)(
            Q + (size_t)(b * L_ + rowb0 + r) * E_ + h * D_ + c4i);
        float* qd = Qt + r * 65 + c4i;
        qd[0] = qv.x; qd[1] = qv.y; qd[2] = qv.z; qd[3] = qv.w;
    }
    float ksl[16];
    #pragma unroll
    for (int ji = 0; ji < 16; ++ji) {
        const int ks = ji >> 3, j = ji & 7;
        ksl[ji] = ksumf[bh * 64 + (ks << 5) + k4 + (j & 3) + ((j >> 2) << 4)];
    }
    __syncthreads();

    // A fragments (phiQ hi/lo) + den from the same rounded weights
    const int rl = (w << 4) + m;         // this lane's q-row (tile-local)
    short8v Ah[2], Al[2];
    float den = 0.f;
    #pragma unroll
    for (int ks = 0; ks < 2; ++ks)
        #pragma unroll
        for (int j = 0; j < 8; ++j) {
            const float qv =
                Qt[rl * 65 + (ks << 5) + k4 + (j & 3) + ((j >> 2) << 4)];
            const float ph = sigk(qv);
            const unsigned short hb = bfh(ph);
            const unsigned short lb = bfh(ph - bf2f(hb));
            Ah[ks][j] = (short)hb;
            Al[ks][j] = (short)lb;
            den = fmaf(bf2f(hb) + bf2f(lb), ksl[(ks << 3) + j], den);
        }

    f32x4 acc[4];
    #pragma unroll
    for (int tt = 0; tt < 4; ++tt) acc[tt] = (f32x4){0.f, 0.f, 0.f, 0.f};
    #pragma unroll
    for (int ks = 0; ks < 2; ++ks)
        #pragma unroll
        for (int tt = 0; tt < 4; ++tt) {
            const int slot = (ks << 2) + tt;
            const short8v Bh = kvH[slot * 64 + l];
            const short8v Bl = kvL[slot * 64 + l];
            acc[tt] = __builtin_amdgcn_mfma_f32_16x16x32_bf16(Ah[ks], Bh, acc[tt], 0, 0, 0);
            acc[tt] = __builtin_amdgcn_mfma_f32_16x16x32_bf16(Ah[ks], Bl, acc[tt], 0, 0, 0);
            acc[tt] = __builtin_amdgcn_mfma_f32_16x16x32_bf16(Al[ks], Bh, acc[tt], 0, 0, 0);
        }

    den += __shfl_xor(den, 16);
    den += __shfl_xor(den, 32);
    float inv[4];
    #pragma unroll
    for (int r = 0; r < 4; ++r)
        inv[r] = __builtin_amdgcn_rcpf(__shfl(den, k4 + r));

    float* op = out + (size_t)(b * L_ + rowb0 + (w << 4)) * E_ + h * D_;
    #pragma unroll
    for (int tt = 0; tt < 4; ++tt)
        #pragma unroll
        for (int r = 0; r < 4; ++r)
            op[(size_t)(k4 + r) * E_ + (tt << 4) + m] = acc[tt][r] * inv[r];
}

extern "C" void kernel_launch(void* const* d_in, const int* in_sizes, int n_in,
                              void* d_out, int out_size, void* d_ws, size_t ws_size,
                              hipStream_t stream) {
    const float* Q = (const float*)d_in[0];
    const float* K = (const float*)d_in[1];
    const float* V = (const float*)d_in[2];
    float* out = (float*)d_out;

    float* partial = (float*)d_ws;                                    // 16*64*4160 f32 (~17 MB)
    unsigned* kv2H = (unsigned*)(partial + (size_t)NCH_ * BH_ * ST2_); // 64*2048 u32 (512 KB)
    unsigned* kv2L = kv2H + (size_t)BH_ * 2048;                        // 512 KB
    float* ksumf   = (float*)(kv2L + (size_t)BH_ * 2048);              // 16 KB

    hipLaunchKernelGGL(kv_partial_kernel, dim3(BH_ * NCH_), dim3(256), 0, stream,
                       K, V, partial);
    hipLaunchKernelGGL(kv_reduce_kernel, dim3(BH_ * 4), dim3(256), 0, stream,
                       partial, kv2H, kv2L, ksumf);
    hipLaunchKernelGGL(attn_out_kernel, dim3(BH_ * 64), dim3(256), 0, stream,
                       Q, kv2H, kv2L, ksumf, out);
}

// Round 16
// 73.048 us; speedup vs baseline: 1.4735x; 1.4735x over previous
//
#include <hip/hip_runtime.h>
#include <cstdint>
#include <cstddef>

#define B_ 4
#define L_ 4096
#define E_ 1024
#define H_ 16
#define D_ 64
#define BH_ 64
#define ST2_ 4160        // 4096 kv + 64 ksum (fp32 partials)
#define NCH_ 16
#define RPC_ (L_/NCH_)   // 256 k-rows per chunk
#define NP_ 4            // 4 single-shot phases of 64 rows
#define LDK_ 68          // padded LDS row stride: all gathers 2-way (free)

typedef __attribute__((ext_vector_type(8))) short short8v;
typedef __attribute__((ext_vector_type(4))) float f32x4;

__device__ __forceinline__ float sigk(float x) {
    // sigmoid(0.6053*x - 4.102) = 1/(1+exp(4.102 - 0.6053*x))
    return __builtin_amdgcn_rcpf(1.0f + __expf(4.102f - 0.6053f * x));
}
// fp32 -> bf16 (RNE) and back, bit ops only
__device__ __forceinline__ unsigned short bfh(float f) {
    union { float f; unsigned u; } v; v.f = f;
    const unsigned r = v.u + 0x7fffu + ((v.u >> 16) & 1u);
    return (unsigned short)(r >> 16);
}
__device__ __forceinline__ float bf2f(unsigned short s) {
    union { unsigned u; float f; } v; v.u = ((unsigned)s) << 16;
    return v.f;
}

// MFMA 16x16x32_bf16 layouts (HW-verified, learn_hip m89/m156/m162):
//   A: lane l holds A[m=l&15][k=4*(l>>4)+(j&3)+16*(j>>2)], j=0..7
//   B: lane l holds B[k(same)][n=l&15]
//   C: lane l, reg r holds C[row=4*(l>>4)+r][col=l&15]

// ---------------- Kernel 1: partial kv[d][e] per (b,h,chunk) ----------------
// K3-CLONE STRUCTURE. K3 moves 128 MiB in ~7us with: single-shot phases,
// float4 staging, one barrier, NO register pipeline -- TLP across blocks hides
// latency. Every pipelined K1 variant (R9-R15) either spilled (runtime-indexed
// prefetch arrays -> scratch, rule #20) or stalled at ~55us. Here: 4 phases of
// {8 named float4 loads -> LDS -> sync -> gather/convert/MFMA -> sync}; no
// register state crosses a barrier, nothing to spill. Per-wave V conversion is
// 4x redundant (~6us chip VALU) -- accepted for structural simplicity.
__global__ void __launch_bounds__(256) kv_partial_kernel(
    const float* __restrict__ K, const float* __restrict__ V,
    float* __restrict__ partial)
{
    __shared__ float rawK[64 * LDK_];   // 17.4 KB
    __shared__ float rawV[64 * LDK_];   // 17.4 KB

    const int ch = blockIdx.x & (NCH_ - 1);
    const int bh = blockIdx.x / NCH_;
    const int b = bh >> 4, h = bh & 15;
    const int tid = threadIdx.x;
    const int w = tid >> 6, l = tid & 63;
    const int g = l >> 4, m = l & 15;
    const int k4 = g << 2;
    const int colA = (w << 4) + m;      // this wave's A d-column
    const int r0 = tid >> 4;            // staging row 0..15 (+16 per i)
    const int c4 = (tid & 15) << 2;     // staging col (float4)

    const float* Kg = K + (size_t)(b * L_ + ch * RPC_) * E_ + h * D_;
    const float* Vg = V + (size_t)(b * L_ + ch * RPC_) * E_ + h * D_;

    f32x4 acc[4];
    #pragma unroll
    for (int t = 0; t < 4; ++t) acc[t] = (f32x4){0.f, 0.f, 0.f, 0.f};
    float ksacc = 0.f;

    for (int p = 0; p < NP_; ++p) {
        // ---- stage 64 rows of K,V: 8 named float4 loads, consumed at once
        const size_t gb = (size_t)((p << 6) + r0) * E_ + c4;
        const float4 ka = *(const float4*)(Kg + gb);
        const float4 kb = *(const float4*)(Kg + gb + (size_t)16 * E_);
        const float4 kc = *(const float4*)(Kg + gb + (size_t)32 * E_);
        const float4 kd = *(const float4*)(Kg + gb + (size_t)48 * E_);
        const float4 va = *(const float4*)(Vg + gb);
        const float4 vb = *(const float4*)(Vg + gb + (size_t)16 * E_);
        const float4 vc = *(const float4*)(Vg + gb + (size_t)32 * E_);
        const float4 vd = *(const float4*)(Vg + gb + (size_t)48 * E_);
        *(float4*)&rawK[(r0     ) * LDK_ + c4] = ka;
        *(float4*)&rawK[(r0 + 16) * LDK_ + c4] = kb;
        *(float4*)&rawK[(r0 + 32) * LDK_ + c4] = kc;
        *(float4*)&rawK[(r0 + 48) * LDK_ + c4] = kd;
        *(float4*)&rawV[(r0     ) * LDK_ + c4] = va;
        *(float4*)&rawV[(r0 + 16) * LDK_ + c4] = vb;
        *(float4*)&rawV[(r0 + 32) * LDK_ + c4] = vc;
        *(float4*)&rawV[(r0 + 48) * LDK_ + c4] = vd;
        __syncthreads();

        // ---- compute: 2 k-steps of 32; all LDS gathers 2-way = free
        #pragma unroll
        for (int ks = 0; ks < 2; ++ks) {
            short8v Ah;
            #pragma unroll
            for (int j = 0; j < 8; ++j) {
                const int k = (ks << 5) + k4 + (j & 3) + ((j >> 2) << 4);
                const unsigned short hb = bfh(sigk(rawK[k * LDK_ + colA]));
                Ah[j] = (short)hb;
                ksacc += bf2f(hb);      // SAME rounded weights as the MFMA
            }
            #pragma unroll
            for (int tt = 0; tt < 4; ++tt) {
                short8v Bh, Bl;
                #pragma unroll
                for (int j = 0; j < 8; ++j) {
                    const int k = (ks << 5) + k4 + (j & 3) + ((j >> 2) << 4);
                    const float vv = rawV[k * LDK_ + (tt << 4) + m];
                    const unsigned short hv = bfh(vv);
                    Bh[j] = (short)hv;
                    Bl[j] = (short)bfh(vv - bf2f(hv));
                }
                acc[tt] = __builtin_amdgcn_mfma_f32_16x16x32_bf16(Ah, Bh, acc[tt], 0, 0, 0);
                acc[tt] = __builtin_amdgcn_mfma_f32_16x16x32_bf16(Ah, Bl, acc[tt], 0, 0, 0);
            }
        }
        __syncthreads();   // before next phase overwrites raw tiles
    }

    // ksum[d]: combine the 4 lane-groups (same m, different k coverage)
    ksacc += __shfl_xor(ksacc, 16);
    ksacc += __shfl_xor(ksacc, 32);

    const size_t pbase = ((size_t)ch * BH_ + bh) * ST2_;
    #pragma unroll
    for (int tt = 0; tt < 4; ++tt)
        #pragma unroll
        for (int r = 0; r < 4; ++r)
            partial[pbase + (size_t)((w << 4) + k4 + r) * 64 + (tt << 4) + m]
                = acc[tt][r];
    if (g == 0) partial[pbase + 4096 + (w << 4) + m] = ksacc;
}

// ---- Kernel 2: reduce partials -> fragment-ordered kv2H / kv2L + ksum ----
// Each thread reduces an even/odd d-pair at one e: the pair lands in the SAME
// fragment u32 (jj even/odd <-> d even/odd), so hi and lo regions are packed
// u32 arrays that K3 copies straight.  Layout: u32[sp(8)][lane(64)][jq(4)].
__global__ void __launch_bounds__(256) kv_reduce_kernel(
    const float* __restrict__ partial, unsigned* __restrict__ kv2H,
    unsigned* __restrict__ kv2L, float* __restrict__ ksumf)
{
    const int bh = blockIdx.x >> 2, part = blockIdx.x & 3;
    const int tid = threadIdx.x;
    const int e = tid & 63;
    #pragma unroll
    for (int it = 0; it < 2; ++it) {
        const int pr = (tid >> 6) + (it << 2);       // 0..7 pair index
        const int d0 = (part << 4) + (pr << 1);      // even d
        float s0 = 0.f, s1 = 0.f;
        #pragma unroll
        for (int c = 0; c < NCH_; ++c) {
            const size_t pb = ((size_t)c * BH_ + bh) * ST2_;
            s0 += partial[pb + (d0 << 6) + e];
            s1 += partial[pb + ((d0 + 1) << 6) + e];
        }
        const unsigned short h0 = bfh(s0), h1 = bfh(s1);
        const unsigned short l0 = bfh(s0 - bf2f(h0));
        const unsigned short l1 = bfh(s1 - bf2f(h1));
        const int kk = d0 & 31;
        const int gg = (kk & 15) >> 2;
        const int jq = ((kk & 3) >> 1) + ((kk >> 4) << 1);   // jj>>1
        const int lane = (e & 15) + (gg << 4);
        const int sp = ((d0 >> 5) << 2) + (e >> 4);
        const size_t idx = (size_t)bh * 2048 + (((sp << 6) + lane) << 2) + jq;
        kv2H[idx] = (unsigned)h0 | ((unsigned)h1 << 16);
        kv2L[idx] = (unsigned)l0 | ((unsigned)l1 << 16);
    }
    if (part == 0 && tid < 64) {
        float s = 0.f;
        #pragma unroll
        for (int c = 0; c < NCH_; ++c)
            s += partial[((size_t)c * BH_ + bh) * ST2_ + 4096 + tid];
        ksumf[bh * 64 + tid] = s;
    }
}

// ---------------- Kernel 3: out = (phiQ @ kv) / (phiQ @ ksum) ----------------
// kvH/kvL staged by straight uint4 copy into short8v[slot][lane] (16B lane
// stride -> conflict-free b128 reads).  Qt: coalesced global float4 reads,
// 2-way-free LDS writes, 4-way (1.58x) scalar fragment gathers.
__global__ void __launch_bounds__(256) attn_out_kernel(
    const float* __restrict__ Q, const unsigned* __restrict__ kv2H,
    const unsigned* __restrict__ kv2L, const float* __restrict__ ksumf,
    float* __restrict__ out)
{
    __shared__ short8v kvH[8 * 64];   // 8 KB
    __shared__ short8v kvL[8 * 64];   // 8 KB
    __shared__ float Qt[64 * 65];     // 16.25 KB

    const int bh = blockIdx.x >> 6, qb = blockIdx.x & 63;
    const int b = bh >> 4, h = bh & 15;
    const int tid = threadIdx.x;
    const int w = tid >> 6, l = tid & 63;
    const int g = l >> 4, m = l & 15;
    const int k4 = g << 2;
    const int rowb0 = qb << 6;

    {   // stage kv fragments: straight copy, coalesced & conflict-free
        const uint4* srcH = (const uint4*)(kv2H + (size_t)bh * 2048);
        const uint4* srcL = (const uint4*)(kv2L + (size_t)bh * 2048);
        uint4* dH = (uint4*)kvH;
        uint4* dL = (uint4*)kvL;
        dH[tid]       = srcH[tid];
        dH[tid + 256] = srcH[tid + 256];
        dL[tid]       = srcL[tid];
        dL[tid + 256] = srcL[tid + 256];
    }
    // stage 64 Q rows (coalesced float4 reads; 2-way-free scalar LDS writes)
    #pragma unroll
    for (int i = 0; i < 4; ++i) {
        const int idx = tid + (i << 8);
        const int r = idx >> 4, c4i = (idx & 15) << 2;
        const float4 qv = *(const float4*)(
            Q + (size_t)(b * L_ + rowb0 + r) * E_ + h * D_ + c4i);
        float* qd = Qt + r * 65 + c4i;
        qd[0] = qv.x; qd[1] = qv.y; qd[2] = qv.z; qd[3] = qv.w;
    }
    float ksl[16];
    #pragma unroll
    for (int ji = 0; ji < 16; ++ji) {
        const int ks = ji >> 3, j = ji & 7;
        ksl[ji] = ksumf[bh * 64 + (ks << 5) + k4 + (j & 3) + ((j >> 2) << 4)];
    }
    __syncthreads();

    // A fragments (phiQ hi/lo) + den from the same rounded weights
    const int rl = (w << 4) + m;         // this lane's q-row (tile-local)
    short8v Ah[2], Al[2];
    float den = 0.f;
    #pragma unroll
    for (int ks = 0; ks < 2; ++ks)
        #pragma unroll
        for (int j = 0; j < 8; ++j) {
            const float qv =
                Qt[rl * 65 + (ks << 5) + k4 + (j & 3) + ((j >> 2) << 4)];
            const float ph = sigk(qv);
            const unsigned short hb = bfh(ph);
            const unsigned short lb = bfh(ph - bf2f(hb));
            Ah[ks][j] = (short)hb;
            Al[ks][j] = (short)lb;
            den = fmaf(bf2f(hb) + bf2f(lb), ksl[(ks << 3) + j], den);
        }

    f32x4 acc[4];
    #pragma unroll
    for (int tt = 0; tt < 4; ++tt) acc[tt] = (f32x4){0.f, 0.f, 0.f, 0.f};
    #pragma unroll
    for (int ks = 0; ks < 2; ++ks)
        #pragma unroll
        for (int tt = 0; tt < 4; ++tt) {
            const int slot = (ks << 2) + tt;
            const short8v Bh = kvH[slot * 64 + l];
            const short8v Bl = kvL[slot * 64 + l];
            acc[tt] = __builtin_amdgcn_mfma_f32_16x16x32_bf16(Ah[ks], Bh, acc[tt], 0, 0, 0);
            acc[tt] = __builtin_amdgcn_mfma_f32_16x16x32_bf16(Ah[ks], Bl, acc[tt], 0, 0, 0);
            acc[tt] = __builtin_amdgcn_mfma_f32_16x16x32_bf16(Al[ks], Bh, acc[tt], 0, 0, 0);
        }

    den += __shfl_xor(den, 16);
    den += __shfl_xor(den, 32);
    float inv[4];
    #pragma unroll
    for (int r = 0; r < 4; ++r)
        inv[r] = __builtin_amdgcn_rcpf(__shfl(den, k4 + r));

    float* op = out + (size_t)(b * L_ + rowb0 + (w << 4)) * E_ + h * D_;
    #pragma unroll
    for (int tt = 0; tt < 4; ++tt)
        #pragma unroll
        for (int r = 0; r < 4; ++r)
            op[(size_t)(k4 + r) * E_ + (tt << 4) + m] = acc[tt][r] * inv[r];
}

extern "C" void kernel_launch(void* const* d_in, const int* in_sizes, int n_in,
                              void* d_out, int out_size, void* d_ws, size_t ws_size,
                              hipStream_t stream) {
    const float* Q = (const float*)d_in[0];
    const float* K = (const float*)d_in[1];
    const float* V = (const float*)d_in[2];
    float* out = (float*)d_out;

    float* partial = (float*)d_ws;                                    // 16*64*4160 f32 (~17 MB)
    unsigned* kv2H = (unsigned*)(partial + (size_t)NCH_ * BH_ * ST2_); // 64*2048 u32 (512 KB)
    unsigned* kv2L = kv2H + (size_t)BH_ * 2048;                        // 512 KB
    float* ksumf   = (float*)(kv2L + (size_t)BH_ * 2048);              // 16 KB

    hipLaunchKernelGGL(kv_partial_kernel, dim3(BH_ * NCH_), dim3(256), 0, stream,
                       K, V, partial);
    hipLaunchKernelGGL(kv_reduce_kernel, dim3(BH_ * 4), dim3(256), 0, stream,
                       partial, kv2H, kv2L, ksumf);
    hipLaunchKernelGGL(attn_out_kernel, dim3(BH_ * 64), dim3(256), 0, stream,
                       Q, kv2H, kv2L, ksumf, out);
}